// Round 19
// baseline (149.347 us; speedup 1.0000x reference)
//
#include <hip/hip_runtime.h>

// ---------------- types ----------------
typedef __attribute__((ext_vector_type(8))) __bf16 bf16x8;
typedef __attribute__((ext_vector_type(4))) __bf16 bf16x4;
typedef __attribute__((ext_vector_type(4))) float f32x4;
typedef __attribute__((ext_vector_type(16))) float f32x16;
typedef __attribute__((ext_vector_type(4))) int i32x4;
typedef __attribute__((ext_vector_type(4))) unsigned short ushort4v;

__device__ __forceinline__ unsigned short f2bf(float f) {
  unsigned u = __builtin_bit_cast(unsigned, f);
  u += 0x7fffu + ((u >> 16) & 1u);   // RNE
  return (unsigned short)(u >> 16);
}

__device__ __forceinline__ unsigned cvt_pk_bf16(float lo, float hi) {
  unsigned r;
  asm("v_cvt_pk_bf16_f32 %0, %1, %2" : "=v"(r) : "v"(lo), "v"(hi));
  return r;
}

// after: a = [a_lo | b_lo], b = [a_hi | b_hi]  (lane halves swapped across regs)
__device__ __forceinline__ void pl32swap(unsigned& a, unsigned& b) {
  asm("v_permlane32_swap_b32 %0, %1" : "+v"(a), "+v"(b));
}

__device__ __forceinline__ void gload16(const void* g, void* l) {
  __builtin_amdgcn_global_load_lds(
      (const __attribute__((address_space(1))) void*)g,
      (__attribute__((address_space(3))) void*)l, 16, 0, 0);
}

// ---------------- convert fp32 -> bf16 + rope tables (merged) ----------------
// grid = 8192 convert blocks + 256 rope blocks (65536 table entries)
__global__ __launch_bounds__(256) void convert_k(
    const float* __restrict__ x, const float* __restrict__ wq,
    const float* __restrict__ wk, const float* __restrict__ wv,
    const float* __restrict__ wo,
    unsigned short* __restrict__ xb, unsigned short* __restrict__ wqkv,
    unsigned short* __restrict__ wob, float* cosT, float* sinT) {
  if (blockIdx.x >= 8192) {   // rope tables: 256 blocks, 2048 x 32
    const int idx = (blockIdx.x - 8192) * 256 + threadIdx.x;
    const int s = idx >> 5, j = idx & 31;
    const float freq = powf(10000.f, -(float)(2 * j) * (1.f / 64.f));
    const float ang = (float)s * freq;
    cosT[idx] = cosf(ang);
    sinT[idx] = sinf(ang);
    return;
  }
  const size_t i = ((size_t)blockIdx.x * 256 + threadIdx.x) * 4;
  const float* src; unsigned short* dst; size_t off;
  if (i < 4194304)      { src = x;  dst = xb;              off = i; }
  else if (i < 5242880) { src = wq; dst = wqkv;            off = i - 4194304; }
  else if (i < 6291456) { src = wk; dst = wqkv + 1048576;  off = i - 5242880; }
  else if (i < 7340032) { src = wv; dst = wqkv + 2097152;  off = i - 6291456; }
  else                  { src = wo; dst = wob;             off = i - 7340032; }
  f32x4 v = *(const f32x4*)(src + off);
  ushort4v o;
  o[0] = f2bf(v[0]); o[1] = f2bf(v[1]); o[2] = f2bf(v[2]); o[3] = f2bf(v[3]);
  *(ushort4v*)(dst + off) = o;
}

// ---------------- GEMM C = A @ B^T: 8-wave 128x128 tile (R12-verified) -------
// 512 threads (8 waves, 2M x 4N of 64x32 wave tiles), BK=64, 16x16x32 MFMA.
// 32KB LDS; 16 waves/CU; cross-block barrier independence hides stage latency.
// LDS XOR-swizzle ((row&7)<<4) with pre-swizzled global_load_lds source.
// T1 XCD-chunked bid swizzle. EPI 0: QKV epilogue; EPI 1: bias + fp32 store.
template <int EPI>
__global__ __launch_bounds__(512) void gemm_bt_k(
    const unsigned short* __restrict__ A, const unsigned short* __restrict__ B,
    int M, int N, int K,
    unsigned short* __restrict__ Qr, unsigned short* __restrict__ Kr,
    unsigned short* __restrict__ Vt,
    const float* __restrict__ bq, const float* __restrict__ bk,
    const float* __restrict__ bvv,
    const float* __restrict__ cosT, const float* __restrict__ sinT,
    float* __restrict__ Cout, const float* __restrict__ bias) {
  __shared__ char smem[32768];   // A tile 16KB | B tile 16KB
  const int t = threadIdx.x;
  const int wave = t >> 6, lane = t & 63;
  const int l15 = lane & 15, g = lane >> 4;
  // T1: XCD-chunked swizzle (grid % 8 == 0 -> bijective)
  const int cpx = (int)gridDim.x >> 3;
  const int wg = (blockIdx.x & 7) * cpx + (blockIdx.x >> 3);
  const int nt = N >> 7;
  const int mb = (wg / nt) << 7;
  const int nb = (wg % nt) << 7;
  const int wm = (wave >> 2) << 6;   // 0 | 64
  const int wn = (wave & 3) << 5;    // 0 | 32 | 64 | 96

  const f32x4 zv = {0.f, 0.f, 0.f, 0.f};
  f32x4 acc[4][2];
#pragma unroll
  for (int i = 0; i < 4; i++)
#pragma unroll
    for (int j = 0; j < 2; j++) acc[i][j] = zv;

  for (int kt = 0; kt < K; kt += 64) {
    // stage: 512 thr x 16B x 2 rounds per 16KB matrix tile
#pragma unroll
    for (int i = 0; i < 2; i++) {
      const int lin = t * 16 + i * 8192;
      const int r = lin >> 7;
      const int cb = (lin & 127) ^ ((r & 7) << 4);   // pre-swizzled source col-byte
      gload16((const char*)A + ((size_t)(mb + r) * K + kt) * 2 + cb,
              smem + i * 8192 + wave * 1024);
      gload16((const char*)B + ((size_t)(nb + r) * K + kt) * 2 + cb,
              smem + 16384 + i * 8192 + wave * 1024);
    }
    __syncthreads();

    bf16x8 af[4][2], bfr[2][2];
    const int sw = (l15 & 7) << 4;
#pragma unroll
    for (int mf = 0; mf < 4; mf++) {
      const int r = wm + mf * 16 + l15;
#pragma unroll
      for (int kf = 0; kf < 2; kf++)
        af[mf][kf] = *(const bf16x8*)(smem + r * 128 + ((kf * 64 + g * 16) ^ sw));
    }
#pragma unroll
    for (int nf = 0; nf < 2; nf++) {
      const int r2 = wn + nf * 16 + l15;
#pragma unroll
      for (int kf = 0; kf < 2; kf++)
        bfr[nf][kf] = *(const bf16x8*)(smem + 16384 + r2 * 128 + ((kf * 64 + g * 16) ^ sw));
    }
#pragma unroll
    for (int mf = 0; mf < 4; mf++)
#pragma unroll
      for (int nf = 0; nf < 2; nf++) {
        acc[mf][nf] = __builtin_amdgcn_mfma_f32_16x16x32_bf16(af[mf][0], bfr[nf][0], acc[mf][nf], 0, 0, 0);
        acc[mf][nf] = __builtin_amdgcn_mfma_f32_16x16x32_bf16(af[mf][1], bfr[nf][1], acc[mf][nf], 0, 0, 0);
      }
    __syncthreads();
  }

  // epilogue: lane element (mf,nf,r): row = mb+wm+mf*16+g*4+r, col = nb+wn+nf*16+l15
#pragma unroll
  for (int mf = 0; mf < 4; mf++) {
#pragma unroll
    for (int nf = 0; nf < 2; nf++) {
      const int row0 = mb + wm + mf * 16 + g * 4;
      const int col = nb + wn + nf * 16 + l15;
      if (EPI == 1) {
        const float bsv = bias[col];
#pragma unroll
        for (int r = 0; r < 4; r++)
          Cout[(size_t)(row0 + r) * N + col] = acc[mf][nf][r] + bsv;
      } else {
        const int region = col >> 10;           // uniform per block (128 | 1024)
        const int cc = col & 1023;
        const int h = cc >> 6, d = cc & 63;
        const float bias_v = (region == 0 ? bq : (region == 1 ? bk : bvv))[cc];
        if (region < 2) {
          unsigned short* Ob = (region == 0 ? Qr : Kr);
          // Q gets 1/sqrt(64) * log2(e) baked in (flash works in exp2 domain)
          const float scl = (region == 0) ? 0.180336880111120425f : 1.0f;
#pragma unroll
          for (int r = 0; r < 4; r++) {
            const int row = row0 + r;
            const int s = row & 2047;
            const int b = row >> 11;
            const float v = acc[mf][nf][r] + bias_v;
            const float p = __shfl_xor(v, 1);
            const float c = cosT[s * 32 + (d >> 1)];
            const float sn = sinT[s * 32 + (d >> 1)];
            float o = (d & 1) ? (v * c + p * sn) : (v * c - p * sn);
            o *= scl;
            Ob[((size_t)(b * 16 + h) * 2048 + s) * 64 + d] = f2bf(o);
          }
        } else {
          ushort4v w;
#pragma unroll
          for (int r = 0; r < 4; r++) w[r] = f2bf(acc[mf][nf][r] + bias_v);
          const int s = row0 & 2047;
          const int b = row0 >> 11;
          *(ushort4v*)(Vt + ((size_t)(b * 16 + h) * 64 + d) * 2048 + s) = w;
        }
      }
    }
  }
}

// ---------------- flash attention v11: K LDS-staged, V direct from L2 --------
// 1024 blocks x 256 threads (4 waves x 32 q-rows, QBLK=128). KV-split x2.
// R6-verified math (fixed-max exp2, in-reg P, VALU lsum). K double-buffered in
// LDS (16KB total); V frags loaded to REGISTERS at iteration start — their
// consumers (PV) run after QK+softmax (~400cyc), which covers L2 latency
// (unlike R9 where K-direct fed QK immediately). Halves LDS traffic: stage
// writes 16->8KB/iter, wave reads 32->16KB/iter. Per-XCD V set 1MB fits L2;
// 4 waves/block share V tiles through L1.
__global__ __launch_bounds__(256, 4) void flash_k(
    const unsigned short* __restrict__ Qr, const unsigned short* __restrict__ Kr,
    const unsigned short* __restrict__ Vt, unsigned short* __restrict__ Op,
    float* __restrict__ Lp) {
  __shared__ char smem[16384];   // [2][K 8KB]
  const int bid = blockIdx.x;
  const int bh = ((bid & 7) << 2) | ((bid >> 3) & 3);   // XCD (bid&7) owns 4 heads
  const int rest = bid >> 5;                            // 0..31
  const int qt = rest & 15;                             // q-tile (128 rows)
  const int ck = rest >> 4;                             // KV chunk 0/1
  const int kvb = ck << 10;
  const int t = threadIdx.x;
  const int wave = t >> 6, lane = t & 63;
  const int l31 = lane & 31, h32 = lane >> 5;
  const int q0 = qt * 128 + wave * 32;
  const unsigned short* Qb = Qr + ((size_t)bh * 2048 + q0) * 64;
  const char* Kb = (const char*)(Kr + (size_t)bh * 2048 * 64);
  const unsigned short* Vb = Vt + (size_t)bh * 64 * 2048;

  // Q B-frags: qB[t4] = Q[q=l31][d = t4*16 + h32*8 + j]
  bf16x8 qB[4];
#pragma unroll
  for (int t4 = 0; t4 < 4; t4++)
    qB[t4] = *(const bf16x8*)(Qb + l31 * 64 + t4 * 16 + h32 * 8);

  const f32x16 z16 = {0,0,0,0,0,0,0,0,0,0,0,0,0,0,0,0};
  f32x16 ot0 = z16, ot1 = z16;
  float lsum = 0.f;
  const int swv = (l31 & 7) << 4;

  // prologue: stage K tile 0 (256 thr x 16B x 2 rounds = 8KB)
#pragma unroll
  for (int i = 0; i < 2; i++) {
    const int lin = t * 16 + i * 4096;
    const int r = lin >> 7;
    const int cb = (lin & 127) ^ ((r & 7) << 4);
    gload16(Kb + (size_t)(kvb + r) * 128 + cb, smem + i * 4096 + wave * 1024);
  }
  __syncthreads();

  for (int it = 0; it < 16; ++it) {
    const int kv0 = kvb + (it << 6);
    const char* kb = smem + (it & 1) * 8192;
    // --- V frags -> registers EARLY (consumed only after QK+softmax) ---
    bf16x8 va[2][2][2];   // [tile][sg][half]
#pragma unroll
    for (int tile = 0; tile < 2; tile++)
#pragma unroll
      for (int sg = 0; sg < 2; sg++) {
        const int kvoff = kv0 + tile * 32 + sg * 16 + h32 * 8;
        va[tile][sg][0] = *(const bf16x8*)(Vb + (size_t)l31 * 2048 + kvoff);
        va[tile][sg][1] = *(const bf16x8*)(Vb + (size_t)(32 + l31) * 2048 + kvoff);
      }
    if (it < 15) {   // stage next K tile (loads in flight through compute)
      const int kvn = kvb + ((it + 1) << 6);
      char* kd = smem + ((it & 1) ^ 1) * 8192;
#pragma unroll
      for (int i = 0; i < 2; i++) {
        const int lin = t * 16 + i * 4096;
        const int r = lin >> 7;
        const int cb = (lin & 127) ^ ((r & 7) << 4);
        gload16(Kb + (size_t)(kvn + r) * 128 + cb, kd + i * 4096 + wave * 1024);
      }
    }
    // --- QK^T: S^T[kv][q], lane: col=q=l31, rows kv=(reg&3)+8*(reg>>2)+4*h32 ---
    f32x16 st0 = z16, st1 = z16;
#pragma unroll
    for (int t4 = 0; t4 < 4; t4++) {
      const bf16x8 ka0 = *(const bf16x8*)(kb + l31 * 128 + ((t4 * 32 + h32 * 16) ^ swv));
      const bf16x8 ka1 = *(const bf16x8*)(kb + (32 + l31) * 128 + ((t4 * 32 + h32 * 16) ^ swv));
      st0 = __builtin_amdgcn_mfma_f32_32x32x16_bf16(ka0, qB[t4], st0, 0, 0, 0);
      st1 = __builtin_amdgcn_mfma_f32_32x32x16_bf16(ka1, qB[t4], st1, 0, 0, 0);
    }
    // --- fixed-max softmax: P = exp2(S - 16), pure sum (no max tracking) ---
    float ls0 = 0.f, ls1 = 0.f;
#pragma unroll
    for (int e = 0; e < 16; e++) {
      const float p0 = __builtin_amdgcn_exp2f(st0[e] - 16.0f);
      const float p1 = __builtin_amdgcn_exp2f(st1[e] - 16.0f);
      st0[e] = p0; st1[e] = p1;
      ls0 += p0; ls1 += p1;
    }
    lsum += ls0 + ls1;
    // --- P -> B-frags in-register: cvt_pk pairs + permlane32_swap; PV ---
#pragma unroll
    for (int tile = 0; tile < 2; tile++) {
      const f32x16& s = tile ? st1 : st0;
#pragma unroll
      for (int sg = 0; sg < 2; sg++) {
        unsigned b0 = cvt_pk_bf16(s[8 * sg + 0], s[8 * sg + 1]);
        unsigned b1 = cvt_pk_bf16(s[8 * sg + 2], s[8 * sg + 3]);
        unsigned b2 = cvt_pk_bf16(s[8 * sg + 4], s[8 * sg + 5]);
        unsigned b3 = cvt_pk_bf16(s[8 * sg + 6], s[8 * sg + 7]);
        pl32swap(b0, b2);
        pl32swap(b1, b3);
        const i32x4 bw = {(int)b0, (int)b1, (int)b2, (int)b3};
        const bf16x8 pb = __builtin_bit_cast(bf16x8, bw);
        ot0 = __builtin_amdgcn_mfma_f32_32x32x16_bf16(va[tile][sg][0], pb, ot0, 0, 0, 0);
        ot1 = __builtin_amdgcn_mfma_f32_32x32x16_bf16(va[tile][sg][1], pb, ot1, 0, 0, 0);
      }
    }
    __syncthreads();   // K stage loads landed (implicit vmcnt drain) + swap
  }
  // epilogue: unnormalized O partial (bf16) + lsum (f32)
  lsum += __shfl_xor(lsum, 32);
  const size_t obase = (((size_t)(ck * 32 + bh)) * 2048 + q0 + l31) * 64;
#pragma unroll
  for (int dt = 0; dt < 2; dt++) {
#pragma unroll
    for (int grp = 0; grp < 4; grp++) {
      bf16x4 w;
#pragma unroll
      for (int e = 0; e < 4; e++)
        w[e] = (__bf16)(dt ? ot1[grp * 4 + e] : ot0[grp * 4 + e]);
      *(bf16x4*)(Op + obase + dt * 32 + grp * 8 + 4 * h32) = w;
    }
  }
  if (lane < 32)
    Lp[((size_t)(ck * 32 + bh)) * 2048 + q0 + l31] = lsum;
}

// ---------------- reduce: Oa = (O0+O1)/(l0+l1), bf16 out ----------------
__global__ __launch_bounds__(256) void reduce_k(
    const unsigned short* __restrict__ Op, const float* __restrict__ Lp,
    unsigned short* __restrict__ Oa) {
  const size_t o = ((size_t)blockIdx.x * 256 + threadIdx.x) * 8;
  const int d0 = (int)(o & 63);
  const int h  = (int)((o >> 6) & 15);
  const int s  = (int)((o >> 10) & 2047);
  const int b  = (int)(o >> 21);
  const size_t pi = (((size_t)(b * 16 + h)) * 2048 + s) * 64 + d0;
  const size_t li = ((size_t)(b * 16 + h)) * 2048 + s;
  const bf16x8 a = *(const bf16x8*)(Op + pi);
  const bf16x8 c = *(const bf16x8*)(Op + pi + 4194304);
  const float inv = 1.f / (Lp[li] + Lp[li + 65536]);
  bf16x8 w;
#pragma unroll
  for (int e = 0; e < 8; e++)
    w[e] = (__bf16)(((float)a[e] + (float)c[e]) * inv);
  *(bf16x8*)(Oa + o) = w;
}

// ---------------- launch ----------------
extern "C" void kernel_launch(void* const* d_in, const int* in_sizes, int n_in,
                              void* d_out, int out_size, void* d_ws, size_t ws_size,
                              hipStream_t stream) {
  const float* x  = (const float*)d_in[0];
  const float* wq = (const float*)d_in[1];
  const float* bq = (const float*)d_in[2];
  const float* wk = (const float*)d_in[3];
  const float* bk = (const float*)d_in[4];
  const float* wv = (const float*)d_in[5];
  const float* bv = (const float*)d_in[6];
  const float* wo = (const float*)d_in[7];
  const float* bo = (const float*)d_in[8];
  float* out = (float*)d_out;
  char* ws = (char*)d_ws;

  // Workspace layout with lifetime overlays (total 44.6 MB):
  //  [0,16.78M): convert/gemm1: xb(8M) wqkv(6M) cos(256K) sin(256K)
  //              flash/reduce:  Opart (2 chunks x 8.39M bf16)
  //  [16.78M):   Qr (8M) [gemm1->flash]; then Oa (8M) [reduce->gemm2]
  //  [25.17M):   Kr (8M)
  //  [33.55M):   Vt (8M)
  //  [41.94M):   wob (2M) [convert->gemm2]
  //  [44.04M):   Lpart (512K)
  unsigned short* xb    = (unsigned short*)(ws);
  unsigned short* wqkv  = (unsigned short*)(ws + 8388608);
  float* cosT           = (float*)(ws + 14680064);
  float* sinT           = (float*)(ws + 14942208);
  unsigned short* Opart = (unsigned short*)(ws);
  unsigned short* Qr    = (unsigned short*)(ws + 16777216);
  unsigned short* Oa    = (unsigned short*)(ws + 16777216);
  unsigned short* Kr    = (unsigned short*)(ws + 25165824);
  unsigned short* Vt    = (unsigned short*)(ws + 33554432);
  unsigned short* wob   = (unsigned short*)(ws + 41943040);
  float* Lpart          = (float*)(ws + 44040192);

  convert_k<<<dim3(8448), dim3(256), 0, stream>>>(x, wq, wk, wv, wo, xb, wqkv, wob, cosT, sinT);
  gemm_bt_k<0><<<dim3(32 * 24), dim3(512), 0, stream>>>(
      xb, wqkv, 4096, 3072, 1024, Qr, Kr, Vt, bq, bk, bv, cosT, sinT,
      (float*)nullptr, (const float*)nullptr);
  flash_k<<<dim3(1024), dim3(256), 0, stream>>>(Qr, Kr, Vt, Opart, Lpart);
  reduce_k<<<dim3(2048), dim3(256), 0, stream>>>(Opart, Lpart, Oa);
  gemm_bt_k<1><<<dim3(32 * 8), dim3(512), 0, stream>>>(
      Oa, wob, 4096, 1024, 1024,
      (unsigned short*)nullptr, (unsigned short*)nullptr, (unsigned short*)nullptr,
      (const float*)nullptr, (const float*)nullptr, (const float*)nullptr,
      cosT, sinT, out, bo);
}

// Round 20
// 115.005 us; speedup vs baseline: 1.2986x; 1.2986x over previous
//
#include <hip/hip_runtime.h>

// ---------------- types ----------------
typedef __attribute__((ext_vector_type(8))) __bf16 bf16x8;
typedef __attribute__((ext_vector_type(4))) __bf16 bf16x4;
typedef __attribute__((ext_vector_type(4))) float f32x4;
typedef __attribute__((ext_vector_type(16))) float f32x16;
typedef __attribute__((ext_vector_type(4))) int i32x4;
typedef __attribute__((ext_vector_type(4))) unsigned short ushort4v;

__device__ __forceinline__ unsigned short f2bf(float f) {
  unsigned u = __builtin_bit_cast(unsigned, f);
  u += 0x7fffu + ((u >> 16) & 1u);   // RNE
  return (unsigned short)(u >> 16);
}

__device__ __forceinline__ unsigned cvt_pk_bf16(float lo, float hi) {
  unsigned r;
  asm("v_cvt_pk_bf16_f32 %0, %1, %2" : "=v"(r) : "v"(lo), "v"(hi));
  return r;
}

// after: a = [a_lo | b_lo], b = [a_hi | b_hi]  (lane halves swapped across regs)
__device__ __forceinline__ void pl32swap(unsigned& a, unsigned& b) {
  asm("v_permlane32_swap_b32 %0, %1" : "+v"(a), "+v"(b));
}

__device__ __forceinline__ void gload16(const void* g, void* l) {
  __builtin_amdgcn_global_load_lds(
      (const __attribute__((address_space(1))) void*)g,
      (__attribute__((address_space(3))) void*)l, 16, 0, 0);
}

// ---------------- convert fp32 -> bf16 + rope tables (merged) ----------------
// grid = 8192 convert blocks + 256 rope blocks (65536 table entries)
__global__ __launch_bounds__(256) void convert_k(
    const float* __restrict__ x, const float* __restrict__ wq,
    const float* __restrict__ wk, const float* __restrict__ wv,
    const float* __restrict__ wo,
    unsigned short* __restrict__ xb, unsigned short* __restrict__ wqkv,
    unsigned short* __restrict__ wob, float* cosT, float* sinT) {
  if (blockIdx.x >= 8192) {   // rope tables: 256 blocks, 2048 x 32
    const int idx = (blockIdx.x - 8192) * 256 + threadIdx.x;
    const int s = idx >> 5, j = idx & 31;
    const float freq = powf(10000.f, -(float)(2 * j) * (1.f / 64.f));
    const float ang = (float)s * freq;
    cosT[idx] = cosf(ang);
    sinT[idx] = sinf(ang);
    return;
  }
  const size_t i = ((size_t)blockIdx.x * 256 + threadIdx.x) * 4;
  const float* src; unsigned short* dst; size_t off;
  if (i < 4194304)      { src = x;  dst = xb;              off = i; }
  else if (i < 5242880) { src = wq; dst = wqkv;            off = i - 4194304; }
  else if (i < 6291456) { src = wk; dst = wqkv + 1048576;  off = i - 5242880; }
  else if (i < 7340032) { src = wv; dst = wqkv + 2097152;  off = i - 6291456; }
  else                  { src = wo; dst = wob;             off = i - 7340032; }
  f32x4 v = *(const f32x4*)(src + off);
  ushort4v o;
  o[0] = f2bf(v[0]); o[1] = f2bf(v[1]); o[2] = f2bf(v[2]); o[3] = f2bf(v[3]);
  *(ushort4v*)(dst + off) = o;
}

// ---------------- GEMM1 C = A @ B^T: 8-wave 128x128 tile (R12-verified) ------
// 512 threads (8 waves, 2M x 4N of 64x32 wave tiles), BK=64, 16x16x32 MFMA.
// 32KB LDS; 16 waves/CU; cross-block barrier independence hides stage latency.
// LDS XOR-swizzle ((row&7)<<4) with pre-swizzled global_load_lds source.
// T1 XCD-chunked bid swizzle. QKV epilogue (bias + RoPE + scale, head-major).
__global__ __launch_bounds__(512) void gemm_bt_k(
    const unsigned short* __restrict__ A, const unsigned short* __restrict__ B,
    int M, int N, int K,
    unsigned short* __restrict__ Qr, unsigned short* __restrict__ Kr,
    unsigned short* __restrict__ Vt,
    const float* __restrict__ bq, const float* __restrict__ bk,
    const float* __restrict__ bvv,
    const float* __restrict__ cosT, const float* __restrict__ sinT) {
  __shared__ char smem[32768];   // A tile 16KB | B tile 16KB
  const int t = threadIdx.x;
  const int wave = t >> 6, lane = t & 63;
  const int l15 = lane & 15, g = lane >> 4;
  // T1: XCD-chunked swizzle (grid % 8 == 0 -> bijective)
  const int cpx = (int)gridDim.x >> 3;
  const int wg = (blockIdx.x & 7) * cpx + (blockIdx.x >> 3);
  const int nt = N >> 7;
  const int mb = (wg / nt) << 7;
  const int nb = (wg % nt) << 7;
  const int wm = (wave >> 2) << 6;   // 0 | 64
  const int wn = (wave & 3) << 5;    // 0 | 32 | 64 | 96

  const f32x4 zv = {0.f, 0.f, 0.f, 0.f};
  f32x4 acc[4][2];
#pragma unroll
  for (int i = 0; i < 4; i++)
#pragma unroll
    for (int j = 0; j < 2; j++) acc[i][j] = zv;

  for (int kt = 0; kt < K; kt += 64) {
    // stage: 512 thr x 16B x 2 rounds per 16KB matrix tile
#pragma unroll
    for (int i = 0; i < 2; i++) {
      const int lin = t * 16 + i * 8192;
      const int r = lin >> 7;
      const int cb = (lin & 127) ^ ((r & 7) << 4);   // pre-swizzled source col-byte
      gload16((const char*)A + ((size_t)(mb + r) * K + kt) * 2 + cb,
              smem + i * 8192 + wave * 1024);
      gload16((const char*)B + ((size_t)(nb + r) * K + kt) * 2 + cb,
              smem + 16384 + i * 8192 + wave * 1024);
    }
    __syncthreads();

    bf16x8 af[4][2], bfr[2][2];
    const int sw = (l15 & 7) << 4;
#pragma unroll
    for (int mf = 0; mf < 4; mf++) {
      const int r = wm + mf * 16 + l15;
#pragma unroll
      for (int kf = 0; kf < 2; kf++)
        af[mf][kf] = *(const bf16x8*)(smem + r * 128 + ((kf * 64 + g * 16) ^ sw));
    }
#pragma unroll
    for (int nf = 0; nf < 2; nf++) {
      const int r2 = wn + nf * 16 + l15;
#pragma unroll
      for (int kf = 0; kf < 2; kf++)
        bfr[nf][kf] = *(const bf16x8*)(smem + 16384 + r2 * 128 + ((kf * 64 + g * 16) ^ sw));
    }
#pragma unroll
    for (int mf = 0; mf < 4; mf++)
#pragma unroll
      for (int nf = 0; nf < 2; nf++) {
        acc[mf][nf] = __builtin_amdgcn_mfma_f32_16x16x32_bf16(af[mf][0], bfr[nf][0], acc[mf][nf], 0, 0, 0);
        acc[mf][nf] = __builtin_amdgcn_mfma_f32_16x16x32_bf16(af[mf][1], bfr[nf][1], acc[mf][nf], 0, 0, 0);
      }
    __syncthreads();
  }

  // epilogue: lane element (mf,nf,r): row = mb+wm+mf*16+g*4+r, col = nb+wn+nf*16+l15
#pragma unroll
  for (int mf = 0; mf < 4; mf++) {
#pragma unroll
    for (int nf = 0; nf < 2; nf++) {
      const int row0 = mb + wm + mf * 16 + g * 4;
      const int col = nb + wn + nf * 16 + l15;
      const int region = col >> 10;           // uniform per block (128 | 1024)
      const int cc = col & 1023;
      const int h = cc >> 6, d = cc & 63;
      const float bias_v = (region == 0 ? bq : (region == 1 ? bk : bvv))[cc];
      if (region < 2) {
        unsigned short* Ob = (region == 0 ? Qr : Kr);
        // Q gets 1/sqrt(64) * log2(e) baked in (flash works in exp2 domain)
        const float scl = (region == 0) ? 0.180336880111120425f : 1.0f;
#pragma unroll
        for (int r = 0; r < 4; r++) {
          const int row = row0 + r;
          const int s = row & 2047;
          const int b = row >> 11;
          const float v = acc[mf][nf][r] + bias_v;
          const float p = __shfl_xor(v, 1);
          const float c = cosT[s * 32 + (d >> 1)];
          const float sn = sinT[s * 32 + (d >> 1)];
          float o = (d & 1) ? (v * c + p * sn) : (v * c - p * sn);
          o *= scl;
          Ob[((size_t)(b * 16 + h) * 2048 + s) * 64 + d] = f2bf(o);
        }
      } else {
        ushort4v w;
#pragma unroll
        for (int r = 0; r < 4; r++) w[r] = f2bf(acc[mf][nf][r] + bias_v);
        const int s = row0 & 2047;
        const int b = row0 >> 11;
        *(ushort4v*)(Vt + ((size_t)(b * 16 + h) * 64 + d) * 2048 + s) = w;
      }
    }
  }
}

// ---------------- GEMM2: 64x128 tile, grid 512 -> 2 blocks/CU (R20 change) ---
// 512 threads (8 waves, 2M x 4N of 32x32 wave tiles), BK=64, K=1024.
// LDS 24KB (A 8KB | B 16KB); 16 waves/CU via 2 resident blocks — same m114
// cross-block TLP mechanism that won R12. Same swizzle algebra.
// Epilogue: bias + fp32 store.
__global__ __launch_bounds__(512) void gemm2_k(
    const unsigned short* __restrict__ A, const unsigned short* __restrict__ B,
    float* __restrict__ Cout, const float* __restrict__ bias) {
  __shared__ char smem[24576];   // A tile 8KB | B tile 16KB
  const int t = threadIdx.x;
  const int wave = t >> 6, lane = t & 63;
  const int l15 = lane & 15, g = lane >> 4;
  const int cpx = (int)gridDim.x >> 3;   // 64; grid 512 % 8 == 0 -> bijective
  const int wg = (blockIdx.x & 7) * cpx + (blockIdx.x >> 3);
  const int mb = (wg >> 3) << 6;    // 64 tiles of 64 rows
  const int nb = (wg & 7) << 7;     // 8 tiles of 128 cols
  const int wm = (wave >> 2) << 5;  // 0 | 32
  const int wn = (wave & 3) << 5;   // 0 | 32 | 64 | 96

  const f32x4 zv = {0.f, 0.f, 0.f, 0.f};
  f32x4 acc[2][2];
#pragma unroll
  for (int i = 0; i < 2; i++)
#pragma unroll
    for (int j = 0; j < 2; j++) acc[i][j] = zv;

  for (int kt = 0; kt < 1024; kt += 64) {
    // stage A: 64x64 = 8KB in 1 round (512 thr x 16B)
    {
      const int r = t >> 3;
      const int cb = ((t & 7) * 16) ^ ((r & 7) << 4);
      gload16((const char*)A + ((size_t)(mb + r) * 1024 + kt) * 2 + cb,
              smem + wave * 1024 + (lane & 63) * 16);
    }
    // stage B: 128x64 = 16KB in 2 rounds
#pragma unroll
    for (int i = 0; i < 2; i++) {
      const int lin = t * 16 + i * 8192;
      const int r = lin >> 7;
      const int cb = (lin & 127) ^ ((r & 7) << 4);
      gload16((const char*)B + ((size_t)(nb + r) * 1024 + kt) * 2 + cb,
              smem + 8192 + i * 8192 + wave * 1024);
    }
    __syncthreads();

    bf16x8 af[2][2], bfr[2][2];
    const int sw = (l15 & 7) << 4;
#pragma unroll
    for (int mf = 0; mf < 2; mf++) {
      const int r = wm + mf * 16 + l15;
#pragma unroll
      for (int kf = 0; kf < 2; kf++)
        af[mf][kf] = *(const bf16x8*)(smem + r * 128 + ((kf * 64 + g * 16) ^ sw));
    }
#pragma unroll
    for (int nf = 0; nf < 2; nf++) {
      const int r2 = wn + nf * 16 + l15;
#pragma unroll
      for (int kf = 0; kf < 2; kf++)
        bfr[nf][kf] = *(const bf16x8*)(smem + 8192 + r2 * 128 + ((kf * 64 + g * 16) ^ sw));
    }
#pragma unroll
    for (int mf = 0; mf < 2; mf++)
#pragma unroll
      for (int nf = 0; nf < 2; nf++) {
        acc[mf][nf] = __builtin_amdgcn_mfma_f32_16x16x32_bf16(af[mf][0], bfr[nf][0], acc[mf][nf], 0, 0, 0);
        acc[mf][nf] = __builtin_amdgcn_mfma_f32_16x16x32_bf16(af[mf][1], bfr[nf][1], acc[mf][nf], 0, 0, 0);
      }
    __syncthreads();
  }

#pragma unroll
  for (int mf = 0; mf < 2; mf++) {
#pragma unroll
    for (int nf = 0; nf < 2; nf++) {
      const int row0 = mb + wm + mf * 16 + g * 4;
      const int col = nb + wn + nf * 16 + l15;
      const float bsv = bias[col];
#pragma unroll
      for (int r = 0; r < 4; r++)
        Cout[(size_t)(row0 + r) * 1024 + col] = acc[mf][nf][r] + bsv;
    }
  }
}

// ---------------- flash attention v6 (R6/R12-verified, 46 us) ----------------
// 1024 blocks x 256 threads (4 waves x 32 q-rows, QBLK=128). KV-split x2
// (1024-kv chunk, 16 iters of KVBLK=64). Fixed softmax max (FM=16) -> no max
// tracking, partials combine linearly. Writes unnormalized O (bf16) + lsum;
// reduce_k normalizes. K/V LDS-staged double-buffered.
__global__ __launch_bounds__(256, 4) void flash_k(
    const unsigned short* __restrict__ Qr, const unsigned short* __restrict__ Kr,
    const unsigned short* __restrict__ Vt, unsigned short* __restrict__ Op,
    float* __restrict__ Lp) {
  __shared__ char smem[32768];   // [2][K 8KB | V 8KB]
  const int bid = blockIdx.x;
  const int bh = ((bid & 7) << 2) | ((bid >> 3) & 3);   // XCD (bid&7) owns 4 heads
  const int rest = bid >> 5;                            // 0..31
  const int qt = rest & 15;                             // q-tile (128 rows)
  const int ck = rest >> 4;                             // KV chunk 0/1
  const int kvb = ck << 10;
  const int t = threadIdx.x;
  const int wave = t >> 6, lane = t & 63;
  const int l31 = lane & 31, h32 = lane >> 5;
  const int q0 = qt * 128 + wave * 32;
  const unsigned short* Qb = Qr + ((size_t)bh * 2048 + q0) * 64;
  const char* Kb = (const char*)(Kr + (size_t)bh * 2048 * 64);
  const char* Vb = (const char*)(Vt + (size_t)bh * 64 * 2048);

  // Q B-frags: qB[t4] = Q[q=l31][d = t4*16 + h32*8 + j]
  bf16x8 qB[4];
#pragma unroll
  for (int t4 = 0; t4 < 4; t4++)
    qB[t4] = *(const bf16x8*)(Qb + l31 * 64 + t4 * 16 + h32 * 8);

  const f32x16 z16 = {0,0,0,0,0,0,0,0,0,0,0,0,0,0,0,0};
  f32x16 ot0 = z16, ot1 = z16;
  float lsum = 0.f;
  const int swv = (l31 & 7) << 4;

  // prologue: stage tile 0 (256 thr x 16B x 2 rounds per 8KB tile)
#pragma unroll
  for (int i = 0; i < 2; i++) {
    const int lin = t * 16 + i * 4096;
    const int r = lin >> 7;
    const int cb = (lin & 127) ^ ((r & 7) << 4);
    gload16(Kb + (size_t)(kvb + r) * 128 + cb, smem + i * 4096 + wave * 1024);
    gload16(Vb + (size_t)r * 4096 + kvb * 2 + cb, smem + 8192 + i * 4096 + wave * 1024);
  }
  __syncthreads();

  for (int it = 0; it < 16; ++it) {
    const char* kb = smem + (it & 1) * 16384;
    const char* vbuf = kb + 8192;
    if (it < 15) {   // stage next tile (loads in flight through compute)
      const int kvn = kvb + ((it + 1) << 6);
      char* kd = smem + ((it & 1) ^ 1) * 16384;
#pragma unroll
      for (int i = 0; i < 2; i++) {
        const int lin = t * 16 + i * 4096;
        const int r = lin >> 7;
        const int cb = (lin & 127) ^ ((r & 7) << 4);
        gload16(Kb + (size_t)(kvn + r) * 128 + cb, kd + i * 4096 + wave * 1024);
        gload16(Vb + (size_t)r * 4096 + kvn * 2 + cb, kd + 8192 + i * 4096 + wave * 1024);
      }
    }
    // --- QK^T: S^T[kv][q], lane: col=q=l31, rows kv=(reg&3)+8*(reg>>2)+4*h32 ---
    f32x16 st0 = z16, st1 = z16;
#pragma unroll
    for (int t4 = 0; t4 < 4; t4++) {
      const bf16x8 ka0 = *(const bf16x8*)(kb + l31 * 128 + ((t4 * 32 + h32 * 16) ^ swv));
      const bf16x8 ka1 = *(const bf16x8*)(kb + (32 + l31) * 128 + ((t4 * 32 + h32 * 16) ^ swv));
      st0 = __builtin_amdgcn_mfma_f32_32x32x16_bf16(ka0, qB[t4], st0, 0, 0, 0);
      st1 = __builtin_amdgcn_mfma_f32_32x32x16_bf16(ka1, qB[t4], st1, 0, 0, 0);
    }
    // --- fixed-max softmax: P = exp2(S - 16), pure sum (no max tracking) ---
    float ls0 = 0.f, ls1 = 0.f;
#pragma unroll
    for (int e = 0; e < 16; e++) {
      const float p0 = __builtin_amdgcn_exp2f(st0[e] - 16.0f);
      const float p1 = __builtin_amdgcn_exp2f(st1[e] - 16.0f);
      st0[e] = p0; st1[e] = p1;
      ls0 += p0; ls1 += p1;
    }
    lsum += ls0 + ls1;
    // --- P -> B-frags in-register: cvt_pk pairs + permlane32_swap ---
#pragma unroll
    for (int tile = 0; tile < 2; tile++) {
      const f32x16& s = tile ? st1 : st0;
#pragma unroll
      for (int sg = 0; sg < 2; sg++) {
        unsigned b0 = cvt_pk_bf16(s[8 * sg + 0], s[8 * sg + 1]);
        unsigned b1 = cvt_pk_bf16(s[8 * sg + 2], s[8 * sg + 3]);
        unsigned b2 = cvt_pk_bf16(s[8 * sg + 4], s[8 * sg + 5]);
        unsigned b3 = cvt_pk_bf16(s[8 * sg + 6], s[8 * sg + 7]);
        pl32swap(b0, b2);
        pl32swap(b1, b3);
        const i32x4 bw = {(int)b0, (int)b1, (int)b2, (int)b3};
        const bf16x8 pb = __builtin_bit_cast(bf16x8, bw);
        const int kvbyte = tile * 64 + sg * 32 + h32 * 16;
        const bf16x8 va0 = *(const bf16x8*)(vbuf + l31 * 128 + (kvbyte ^ swv));
        const bf16x8 va1 = *(const bf16x8*)(vbuf + (32 + l31) * 128 + (kvbyte ^ swv));
        ot0 = __builtin_amdgcn_mfma_f32_32x32x16_bf16(va0, pb, ot0, 0, 0, 0);
        ot1 = __builtin_amdgcn_mfma_f32_32x32x16_bf16(va1, pb, ot1, 0, 0, 0);
      }
    }
    __syncthreads();   // stage loads landed (implicit vmcnt drain) + buffer swap
  }
  // epilogue: unnormalized O partial (bf16) + lsum (f32)
  lsum += __shfl_xor(lsum, 32);
  const size_t obase = (((size_t)(ck * 32 + bh)) * 2048 + q0 + l31) * 64;
#pragma unroll
  for (int dt = 0; dt < 2; dt++) {
#pragma unroll
    for (int grp = 0; grp < 4; grp++) {
      bf16x4 w;
#pragma unroll
      for (int e = 0; e < 4; e++)
        w[e] = (__bf16)(dt ? ot1[grp * 4 + e] : ot0[grp * 4 + e]);
      *(bf16x4*)(Op + obase + dt * 32 + grp * 8 + 4 * h32) = w;
    }
  }
  if (lane < 32)
    Lp[((size_t)(ck * 32 + bh)) * 2048 + q0 + l31] = lsum;
}

// ---------------- reduce: Oa = (O0+O1)/(l0+l1), bf16 out ----------------
__global__ __launch_bounds__(256) void reduce_k(
    const unsigned short* __restrict__ Op, const float* __restrict__ Lp,
    unsigned short* __restrict__ Oa) {
  const size_t o = ((size_t)blockIdx.x * 256 + threadIdx.x) * 8;
  const int d0 = (int)(o & 63);
  const int h  = (int)((o >> 6) & 15);
  const int s  = (int)((o >> 10) & 2047);
  const int b  = (int)(o >> 21);
  const size_t pi = (((size_t)(b * 16 + h)) * 2048 + s) * 64 + d0;
  const size_t li = ((size_t)(b * 16 + h)) * 2048 + s;
  const bf16x8 a = *(const bf16x8*)(Op + pi);
  const bf16x8 c = *(const bf16x8*)(Op + pi + 4194304);
  const float inv = 1.f / (Lp[li] + Lp[li + 65536]);
  bf16x8 w;
#pragma unroll
  for (int e = 0; e < 8; e++)
    w[e] = (__bf16)(((float)a[e] + (float)c[e]) * inv);
  *(bf16x8*)(Oa + o) = w;
}

// ---------------- launch ----------------
extern "C" void kernel_launch(void* const* d_in, const int* in_sizes, int n_in,
                              void* d_out, int out_size, void* d_ws, size_t ws_size,
                              hipStream_t stream) {
  const float* x  = (const float*)d_in[0];
  const float* wq = (const float*)d_in[1];
  const float* bq = (const float*)d_in[2];
  const float* wk = (const float*)d_in[3];
  const float* bk = (const float*)d_in[4];
  const float* wv = (const float*)d_in[5];
  const float* bv = (const float*)d_in[6];
  const float* wo = (const float*)d_in[7];
  const float* bo = (const float*)d_in[8];
  float* out = (float*)d_out;
  char* ws = (char*)d_ws;

  // Workspace layout with lifetime overlays (total 44.6 MB):
  //  [0,16.78M): convert/gemm1: xb(8M) wqkv(6M) cos(256K) sin(256K)
  //              flash/reduce:  Opart (2 chunks x 8.39M bf16)
  //  [16.78M):   Qr (8M) [gemm1->flash]; then Oa (8M) [reduce->gemm2]
  //  [25.17M):   Kr (8M)
  //  [33.55M):   Vt (8M)
  //  [41.94M):   wob (2M) [convert->gemm2]
  //  [44.04M):   Lpart (512K)
  unsigned short* xb    = (unsigned short*)(ws);
  unsigned short* wqkv  = (unsigned short*)(ws + 8388608);
  float* cosT           = (float*)(ws + 14680064);
  float* sinT           = (float*)(ws + 14942208);
  unsigned short* Opart = (unsigned short*)(ws);
  unsigned short* Qr    = (unsigned short*)(ws + 16777216);
  unsigned short* Oa    = (unsigned short*)(ws + 16777216);
  unsigned short* Kr    = (unsigned short*)(ws + 25165824);
  unsigned short* Vt    = (unsigned short*)(ws + 33554432);
  unsigned short* wob   = (unsigned short*)(ws + 41943040);
  float* Lpart          = (float*)(ws + 44040192);

  convert_k<<<dim3(8448), dim3(256), 0, stream>>>(x, wq, wk, wv, wo, xb, wqkv, wob, cosT, sinT);
  gemm_bt_k<<<dim3(32 * 24), dim3(512), 0, stream>>>(
      xb, wqkv, 4096, 3072, 1024, Qr, Kr, Vt, bq, bk, bv, cosT, sinT);
  flash_k<<<dim3(1024), dim3(256), 0, stream>>>(Qr, Kr, Vt, Opart, Lpart);
  reduce_k<<<dim3(2048), dim3(256), 0, stream>>>(Opart, Lpart, Oa);
  gemm2_k<<<dim3(512), dim3(512), 0, stream>>>(Oa, wob, out, bo);
}